// Round 8
// baseline (269.766 us; speedup 1.0000x reference)
//
#include <hip/hip_runtime.h>
#include <math.h>

#define S_LEN 2048
#define D_DIM 128
#define BHN   32
#define NKT   32                  // KV tiles of 64
#define TILE_ELEMS (64 * 128)
#define LOG2E 1.44269504088896340736f

typedef _Float16 f16;
typedef __attribute__((ext_vector_type(4))) _Float16 f16x4;
typedef __attribute__((ext_vector_type(8))) _Float16 f16x8;
typedef __attribute__((ext_vector_type(4))) float    f32x4;

__device__ __forceinline__ void async_cp16(const void* g, void* l) {
  __builtin_amdgcn_global_load_lds(
      (const __attribute__((address_space(1))) unsigned int*)g,
      (__attribute__((address_space(3))) unsigned int*)l,
      16, 0, 0);
}

// ---- prepass (verbatim from R5 — proven with these LDS tile layouts).
__global__ __launch_bounds__(256) void prep_kernel(const float* __restrict__ k,
                                                   const float* __restrict__ v,
                                                   f16* __restrict__ kw,
                                                   f16* __restrict__ vtw) {
  __shared__ f16 Vimg[D_DIM * 64];
  const int bx = blockIdx.x;
  const int bh = bx >> 5;
  const int jt = bx & 31;
  const int t  = threadIdx.x;
  {
    const float* kbase = k + ((size_t)bh * S_LEN + jt * 64) * D_DIM;
    f16* ktile = kw + (((size_t)bh * NKT + jt) * 64) * (size_t)D_DIM;
#pragma unroll
    for (int i = 0; i < 4; ++i) {
      int unit = i * 256 + t;
      int kd = unit & 15;
      int r  = unit >> 4;
      const float* src = kbase + r * D_DIM + kd * 8;
      float4 a = *(const float4*)src;
      float4 b = *(const float4*)(src + 4);
      f16x8 vv;
      vv[0]=(f16)a.x; vv[1]=(f16)a.y; vv[2]=(f16)a.z; vv[3]=(f16)a.w;
      vv[4]=(f16)b.x; vv[5]=(f16)b.y; vv[6]=(f16)b.z; vv[7]=(f16)b.w;
      *(f16x8*)(ktile + r * D_DIM + ((kd ^ (r & 15)) * 8)) = vv;
    }
  }
  {
    const int rq = t >> 4;
    const int dg = t & 15;
    const float* base = v + (((size_t)bh * S_LEN + jt * 64 + rq * 4) * D_DIM + dg * 8);
    float rows[4][8];
#pragma unroll
    for (int rr = 0; rr < 4; ++rr) {
      float4 aa = *(const float4*)(base + rr * D_DIM);
      float4 bb = *(const float4*)(base + rr * D_DIM + 4);
      rows[rr][0]=aa.x; rows[rr][1]=aa.y; rows[rr][2]=aa.z; rows[rr][3]=aa.w;
      rows[rr][4]=bb.x; rows[rr][5]=bb.y; rows[rr][6]=bb.z; rows[rr][7]=bb.w;
    }
    const int kc = rq >> 1;
    const int kk = (rq & 1) * 4;
#pragma unroll
    for (int dd0 = 0; dd0 < 8; ++dd0) {
      int dd = (dd0 + dg) & 7;
      int d  = dg * 8 + dd;
      f16x4 p;
      p[0]=(f16)rows[0][dd]; p[1]=(f16)rows[1][dd];
      p[2]=(f16)rows[2][dd]; p[3]=(f16)rows[3][dd];
      *(f16x4*)(Vimg + d * 64 + ((kc ^ dd) * 8) + kk) = p;
    }
    __syncthreads();
    f16* vtile = vtw + ((size_t)bh * NKT + jt) * (size_t)(D_DIM * 64);
#pragma unroll
    for (int i = 0; i < 4; ++i) {
      int idx = i * 256 + t;
      *(f16x8*)(vtile + idx * 8) = *(const f16x8*)(Vimg + idx * 8);
    }
  }
}

// ---- main: 2-strip flash attention, skewed single-buffer pipeline, split-KV.
// Per iter: [stage K_j] [PV_{j-1}] [barrier A] [stage V_j] [QK_j] [barrier B]
// [softmax_j -> P_j]. Both barriers' implicit vmcnt(0) drain loads issued
// 600-800 cycles earlier. Each K/V fragment read feeds 2 strips. 1024 blocks
// (16 tiles x 2 KV-halves x 32 bh), exactly qt+1 iters per block-half.
__global__ __launch_bounds__(256) void attn_kernel(const float* __restrict__ q,
                                                   const f16* __restrict__ kw,
                                                   const f16* __restrict__ vtw,
                                                   const float* __restrict__ am,
                                                   f16* __restrict__ Ow,
                                                   float* __restrict__ Mw,
                                                   float* __restrict__ Lw) {
  __shared__ f16 Klds[64 * 128];    // 16 KB
  __shared__ f16 Vlds[64 * 128];    // 16 KB
  __shared__ f16 Plds[128 * 68];    // 17 KB, stride-68 (R5-measured 0 conflicts)

  const int bx   = blockIdx.x;           // 1024
  const int bh   = bx & 31;
  const int uu   = 31 - (bx >> 5);       // heavy (qt=15) first
  const int qt   = uu >> 1;              // Q-tile of 128 rows
  const int h    = uu & 1;               // KV half
  const int jbase = h ? (qt + 1) : 0;
  const int jend  = h ? (2 * qt + 1) : qt;
  const int slot  = (qt * 2 + h) * 32 + bh;
  const int b    = bh >> 4;
  const int t    = threadIdx.x;
  const int w    = t >> 6;
  const int lane = t & 63;
  const int c    = lane & 15;
  const int quad = lane >> 4;
  const int e2   = (c & 7) << 1;

  int sidx[4];
#pragma unroll
  for (int r = 0; r < 4; ++r) sidx[r] = (lane & 48) | (quad * 4 + r);

  // Q fragments for both strips (B operand of S^T = K Q^T), pre-scaled log2e
  f16x8 qf[2][4];
#pragma unroll
  for (int s = 0; s < 2; ++s) {
    const float* qsrc = q + (((size_t)bh * S_LEN + qt * 128 + s * 64 + w * 16 + c) * D_DIM + quad * 8);
#pragma unroll
    for (int ks = 0; ks < 4; ++ks) {
      float4 a  = *(const float4*)(qsrc + ks * 32);
      float4 bb = *(const float4*)(qsrc + ks * 32 + 4);
      f16x8 vv;
      vv[0]=(f16)(a.x*LOG2E);  vv[1]=(f16)(a.y*LOG2E);  vv[2]=(f16)(a.z*LOG2E);  vv[3]=(f16)(a.w*LOG2E);
      vv[4]=(f16)(bb.x*LOG2E); vv[5]=(f16)(bb.y*LOG2E); vv[6]=(f16)(bb.z*LOG2E); vv[7]=(f16)(bb.w*LOG2E);
      qf[s][ks] = vv;
    }
  }

  const float* amp = am + (size_t)b * S_LEN;

  f32x4 zero4; zero4[0]=0.f; zero4[1]=0.f; zero4[2]=0.f; zero4[3]=0.f;
  f32x4 oacc[2][8];
#pragma unroll
  for (int s = 0; s < 2; ++s)
#pragma unroll
    for (int dt = 0; dt < 8; ++dt) oacc[s][dt] = zero4;
  float mrow[2] = {-INFINITY, -INFINITY};
  float lrow[2] = {0.f, 0.f};
  float alp[2][4];                        // deferred O-rescale factors

  const f16* ktiles = kw  + (size_t)bh * NKT * TILE_ELEMS;
  const f16* vtiles = vtw + (size_t)bh * NKT * TILE_ELEMS;

  for (int j = jbase; j <= jend; ++j) {
    // (1) stage K_j (Klds readers confirmed done by barrier B of prev iter)
    {
      const f16* kg = ktiles + (size_t)j * TILE_ELEMS + (w * 4) * 512 + lane * 8;
      f16* kl = Klds + (w * 4) * 512;
#pragma unroll
      for (int i = 0; i < 4; ++i) async_cp16(kg + i * 512, kl + i * 512);
    }
    float amv[4][4];
#pragma unroll
    for (int nt = 0; nt < 4; ++nt) {
      float4 a4 = *(const float4*)(amp + j * 64 + nt * 16 + quad * 4);
      amv[nt][0]=a4.x*LOG2E; amv[nt][1]=a4.y*LOG2E; amv[nt][2]=a4.z*LOG2E; amv[nt][3]=a4.w*LOG2E;
    }

    // (2) deferred rescale + PV_{j-1} (covers K_j flight; Vlds still holds j-1)
    if (j != jbase) {
#pragma unroll
      for (int s = 0; s < 2; ++s)
#pragma unroll
        for (int dt = 0; dt < 8; ++dt)
#pragma unroll
          for (int r = 0; r < 4; ++r) oacc[s][dt][r] *= alp[s][r];
#pragma unroll
      for (int ks2 = 0; ks2 < 2; ++ks2) {
        const int ch2 = (ks2 * 8 + quad * 2) ^ e2;
        const f16x8 af0 = *(const f16x8*)(Plds + (w * 16 + c) * 68 + ch2 * 4);
        const f16x8 af1 = *(const f16x8*)(Plds + (64 + w * 16 + c) * 68 + ch2 * 4);
#pragma unroll
        for (int dt = 0; dt < 8; ++dt) {
          const f16x8 bf = *(const f16x8*)(Vlds + (dt * 16 + c) * 64 + (((ks2 * 4 + quad) ^ (c & 7)) * 8));
          oacc[0][dt] = __builtin_amdgcn_mfma_f32_16x16x32_f16(af0, bf, oacc[0][dt], 0, 0, 0);
          oacc[1][dt] = __builtin_amdgcn_mfma_f32_16x16x32_f16(af1, bf, oacc[1][dt], 0, 0, 0);
        }
      }
    }

    __syncthreads();   // A: PV reads of Vlds done; K_j (issued ~800cy ago) drained

    // (3) stage V_j (in flight across QK)
    {
      const f16* vg = vtiles + (size_t)j * TILE_ELEMS + (w * 4) * 512 + lane * 8;
      f16* vl = Vlds + (w * 4) * 512;
#pragma unroll
      for (int i = 0; i < 4; ++i) async_cp16(vg + i * 512, vl + i * 512);
    }

    // (4) QK: S^T = K Q^T, each kf feeds both strips
    f32x4 sacc[2][4];
#pragma unroll
    for (int s = 0; s < 2; ++s)
#pragma unroll
      for (int nt = 0; nt < 4; ++nt) sacc[s][nt] = zero4;
#pragma unroll
    for (int ks = 0; ks < 4; ++ks) {
#pragma unroll
      for (int nt = 0; nt < 4; ++nt) {
        const f16x8 kf = *(const f16x8*)(Klds + (nt * 16 + c) * 128 + (((ks * 4 + quad) ^ c) * 8));
        sacc[0][nt] = __builtin_amdgcn_mfma_f32_16x16x32_f16(kf, qf[0][ks], sacc[0][nt], 0, 0, 0);
        sacc[1][nt] = __builtin_amdgcn_mfma_f32_16x16x32_f16(kf, qf[1][ks], sacc[1][nt], 0, 0, 0);
      }
    }

    __syncthreads();   // B: QK reads of Klds done; V_j (issued ~700cy ago) drained

    // (5) mask + softmax + P write per strip
    const bool diag = (j >= 2 * qt);
#pragma unroll
    for (int s = 0; s < 2; ++s) {
      if (diag) {
        const int grow = qt * 128 + s * 64 + w * 16 + c;
#pragma unroll
        for (int nt = 0; nt < 4; ++nt)
#pragma unroll
          for (int r = 0; r < 4; ++r)
            if (j * 64 + nt * 16 + quad * 4 + r > grow) sacc[s][nt][r] = -INFINITY;
      }
#pragma unroll
      for (int nt = 0; nt < 4; ++nt)
#pragma unroll
        for (int r = 0; r < 4; ++r) sacc[s][nt][r] += amv[nt][r];

      float m16 = sacc[s][0][0];
#pragma unroll
      for (int nt = 0; nt < 4; ++nt)
#pragma unroll
        for (int r = 0; r < 4; ++r) m16 = fmaxf(m16, sacc[s][nt][r]);
      m16 = fmaxf(m16, __shfl_xor(m16, 16));
      m16 = fmaxf(m16, __shfl_xor(m16, 32));
      float mnew = fmaxf(fmaxf(mrow[s], m16), -1e30f);  // clamp: all-masked -> -1e30
      float alpha = exp2f(mrow[s] - mnew);               // -inf first iter -> 0 (oacc=0)
      mrow[s] = mnew;

      float psum = 0.f;
#pragma unroll
      for (int nt = 0; nt < 4; ++nt)
#pragma unroll
        for (int r = 0; r < 4; ++r) {
          sacc[s][nt][r] = exp2f(sacc[s][nt][r] - mnew);
          psum += sacc[s][nt][r];
        }
      lrow[s] = lrow[s] * alpha + psum;

#pragma unroll
      for (int nt = 0; nt < 4; ++nt) {
        f16x4 p;
        p[0]=(f16)sacc[s][nt][0]; p[1]=(f16)sacc[s][nt][1];
        p[2]=(f16)sacc[s][nt][2]; p[3]=(f16)sacc[s][nt][3];
        int ch = (nt * 4 + quad) ^ e2;
        *(f16x4*)(Plds + (s * 64 + w * 16 + c) * 68 + ch * 4) = p;
      }
#pragma unroll
      for (int r = 0; r < 4; ++r) alp[s][r] = __shfl(alpha, sidx[r]);
    }
  }

  // final PV (P, Vlds from last iter; within-wave P rows, V resident since A)
#pragma unroll
  for (int s = 0; s < 2; ++s)
#pragma unroll
    for (int dt = 0; dt < 8; ++dt)
#pragma unroll
      for (int r = 0; r < 4; ++r) oacc[s][dt][r] *= alp[s][r];
#pragma unroll
  for (int ks2 = 0; ks2 < 2; ++ks2) {
    const int ch2 = (ks2 * 8 + quad * 2) ^ e2;
    const f16x8 af0 = *(const f16x8*)(Plds + (w * 16 + c) * 68 + ch2 * 4);
    const f16x8 af1 = *(const f16x8*)(Plds + (64 + w * 16 + c) * 68 + ch2 * 4);
#pragma unroll
    for (int dt = 0; dt < 8; ++dt) {
      const f16x8 bf = *(const f16x8*)(Vlds + (dt * 16 + c) * 64 + (((ks2 * 4 + quad) ^ (c & 7)) * 8));
      oacc[0][dt] = __builtin_amdgcn_mfma_f32_16x16x32_f16(af0, bf, oacc[0][dt], 0, 0, 0);
      oacc[1][dt] = __builtin_amdgcn_mfma_f32_16x16x32_f16(af1, bf, oacc[1][dt], 0, 0, 0);
    }
  }

  // epilogue: write partials (O' f16 unnormalized, m clamped, l per row)
  f16* op = Ow + (size_t)slot * (128 * 128);
#pragma unroll
  for (int s = 0; s < 2; ++s) {
    float l = lrow[s];
    l += __shfl_xor(l, 16);
    l += __shfl_xor(l, 32);
    if (quad == 0) {
      Mw[(size_t)slot * 128 + s * 64 + w * 16 + c] = mrow[s];
      Lw[(size_t)slot * 128 + s * 64 + w * 16 + c] = l;
    }
#pragma unroll
    for (int dt = 0; dt < 8; ++dt)
#pragma unroll
      for (int r = 0; r < 4; ++r)
        op[(s * 64 + w * 16 + quad * 4 + r) * 128 + dt * 16 + c] = (f16)oacc[s][dt][r];
  }
}

// ---- merge: out = (a1*O1 + a2*O2) * hm / (a1*l1 + a2*l2), exp2 domain
__global__ __launch_bounds__(256) void merge_kernel(const f16* __restrict__ Ow,
                                                    const float* __restrict__ Mw,
                                                    const float* __restrict__ Lw,
                                                    const float* __restrict__ hm,
                                                    float* __restrict__ out) {
  const int bx = blockIdx.x;        // 512 = 32 bh x 16 qt
  const int bh = bx & 31;
  const int qt = bx >> 5;
  const int t  = threadIdx.x;
  const int row = t >> 1;
  const int dh  = (t & 1) * 64;

  const int s0 = (qt * 2) * 32 + bh;
  const int s1 = s0 + 32;
  float m1 = Mw[(size_t)s0 * 128 + row], l1 = Lw[(size_t)s0 * 128 + row];
  float m2 = Mw[(size_t)s1 * 128 + row], l2 = Lw[(size_t)s1 * 128 + row];
  float m  = fmaxf(m1, m2);
  float a1 = exp2f(m1 - m), a2 = exp2f(m2 - m);
  float hmv = hm[bh & 15];
  float inv = hmv / (a1 * l1 + a2 * l2);
  float c1 = a1 * inv, c2 = a2 * inv;

  const f16* o1 = Ow + (size_t)s0 * (128 * 128) + row * 128 + dh;
  const f16* o2 = Ow + (size_t)s1 * (128 * 128) + row * 128 + dh;
  float* po = out + (((size_t)bh * S_LEN + qt * 128 + row) * D_DIM + dh);
#pragma unroll
  for (int i = 0; i < 8; ++i) {
    f16x8 x1 = *(const f16x8*)(o1 + i * 8);
    f16x8 x2 = *(const f16x8*)(o2 + i * 8);
    float4 r0, r1;
    r0.x = (float)x1[0]*c1 + (float)x2[0]*c2;
    r0.y = (float)x1[1]*c1 + (float)x2[1]*c2;
    r0.z = (float)x1[2]*c1 + (float)x2[2]*c2;
    r0.w = (float)x1[3]*c1 + (float)x2[3]*c2;
    r1.x = (float)x1[4]*c1 + (float)x2[4]*c2;
    r1.y = (float)x1[5]*c1 + (float)x2[5]*c2;
    r1.z = (float)x1[6]*c1 + (float)x2[6]*c2;
    r1.w = (float)x1[7]*c1 + (float)x2[7]*c2;
    *(float4*)(po + i * 8)     = r0;
    *(float4*)(po + i * 8 + 4) = r1;
  }
}

extern "C" void kernel_launch(void* const* d_in, const int* in_sizes, int n_in,
                              void* d_out, int out_size, void* d_ws, size_t ws_size,
                              hipStream_t stream) {
  const float* q  = (const float*)d_in[0];
  const float* k  = (const float*)d_in[1];
  const float* v  = (const float*)d_in[2];
  const float* am = (const float*)d_in[3];
  const float* hm = (const float*)d_in[4];
  float* out = (float*)d_out;

  f16* kw   = (f16*)d_ws;                 // 16.78 MB
  f16* vtw  = kw  + 8388608;              // 16.78 MB
  f16* Ow   = vtw + 8388608;              // 33.55 MB (1024 slots x 128x128 f16)
  float* Mw = (float*)(Ow + 16777216);    // 0.52 MB
  float* Lw = Mw + 131072;                // 0.52 MB   total 68.4 MB

  prep_kernel<<<1024, 256, 0, stream>>>(k, v, kw, vtw);
  attn_kernel<<<1024, 256, 0, stream>>>(q, kw, vtw, am, Ow, Mw, Lw);
  merge_kernel<<<512, 256, 0, stream>>>(Ow, Mw, Lw, hm, out);
}